// Round 4
// baseline (26818.134 us; speedup 1.0000x reference)
//
#include <hip/hip_runtime.h>
#include <hip/hip_bf16.h>

#define SEQ   512
#define BATCH 256
#define DIN   512
#define DLAT  1024

#define NBG   16                 // batch groups of 16 rows
#define NCG   8                  // col groups of 128 cols
#define NFLAGS (NBG * 64)        // per-wave flags: 16 bg x (8 cg x 8 waves)

typedef __attribute__((ext_vector_type(8))) short bf16x8;
typedef __attribute__((ext_vector_type(4))) float f32x4;
typedef unsigned long long u64;

__device__ __forceinline__ unsigned short f2bf(float f) {
    union { float f; unsigned u; } v; v.f = f;
    unsigned r = v.u + 0x7FFFu + ((v.u >> 16) & 1u);   // RNE
    return (unsigned short)(r >> 16);
}

__global__ void convert_weights(const float* __restrict__ Wi, const float* __restrict__ Wh,
                                unsigned short* __restrict__ Wib, unsigned short* __restrict__ Whb,
                                unsigned int* __restrict__ flags) {
    const int nWi = DLAT * DIN;
    const int nWh = DLAT * DLAT;
    const int t0 = blockIdx.x * blockDim.x + threadIdx.x;
    if (t0 < NFLAGS) flags[t0] = 0;
    for (int idx = t0; idx < nWi + nWh; idx += gridDim.x * blockDim.x) {
        if (idx < nWi) Wib[idx] = f2bf(Wi[idx]);
        else           Whb[idx - nWi] = f2bf(Wh[idx - nWi]);
    }
}

// Phase 1: xi = x @ Wi^T. (validated rounds 1-3)
__global__ __launch_bounds__(1024) void xproj_kernel(const float* __restrict__ x,
                                                     const unsigned short* __restrict__ Wib,
                                                     float* __restrict__ xi) {
    const int tid  = threadIdx.x;
    const int lane = tid & 63;
    const int w    = tid >> 6;
    const int l15  = lane & 15;
    const int l4   = lane >> 4;
    const int mblk = blockIdx.x >> 2;
    const int nblk = blockIdx.x & 3;
    const size_t m0 = (size_t)mblk * 64 + (w & 3) * 16;
    const int    n0 = nblk * 256 + (w >> 2) * 64;

    const float* xp = x + (m0 + l15) * DIN + l4 * 8;

    f32x4 acc[4];
    #pragma unroll
    for (int j = 0; j < 4; ++j) acc[j] = (f32x4)0.f;

    const unsigned short* bp[4];
    #pragma unroll
    for (int j = 0; j < 4; ++j)
        bp[j] = Wib + (size_t)(n0 + j * 16 + l15) * DIN + l4 * 8;

    #pragma unroll 4
    for (int kc = 0; kc < DIN / 32; ++kc) {
        f32x4 a0 = *(const f32x4*)(xp + kc * 32);
        f32x4 a1 = *(const f32x4*)(xp + kc * 32 + 4);
        bf16x8 af;
        #pragma unroll
        for (int i = 0; i < 4; ++i) { af[i] = (short)f2bf(a0[i]); af[i + 4] = (short)f2bf(a1[i]); }
        #pragma unroll
        for (int j = 0; j < 4; ++j) {
            bf16x8 bf = *(const bf16x8*)(bp[j] + kc * 32);
            acc[j] = __builtin_amdgcn_mfma_f32_16x16x32_bf16(af, bf, acc[j], 0, 0, 0);
        }
    }
    #pragma unroll
    for (int j = 0; j < 4; ++j) {
        const int col = n0 + j * 16 + l15;
        #pragma unroll
        for (int i = 0; i < 4; ++i)
            xi[(m0 + l4 * 4 + i) * DLAT + col] = acc[j][i];
    }
}

// Phase 2: 128 blocks = 16 bg x 8 cg, 512 thr (8 waves, 16 cols each).
// h exchanged via agent-scope hbuf (double-buffered bf16) staged into a
// double-buffered XOR-swizzled LDS tile. bg-local per-wave flag barrier
// (release store / acquire spin) replaces grid.sync. W_h streamed from L2.
__global__ __launch_bounds__(512, 1) void rnn_scan(
        const unsigned short* __restrict__ Whb,
        const float* __restrict__ bh,
        float* __restrict__ hs,                 // xi on entry; overwritten with h
        float* __restrict__ hfin,
        unsigned short* __restrict__ hbuf,      // [2][BATCH][DLAT] bf16
        unsigned int* __restrict__ flags) {     // [NBG][64] monotone counters
    __shared__ unsigned short tile[2][16][1024];   // 64 KB, rows XOR-swizzled

    const int tid  = threadIdx.x;
    const int lane = tid & 63;
    const int w    = tid >> 6;        // 0..7
    const int l15  = lane & 15;
    const int l4   = lane >> 4;       // 0..3
    const int bg   = blockIdx.x >> 3; // 0..15
    const int cg   = blockIdx.x & 7;  // 0..7
    const int b0   = bg * 16;
    const int col  = cg * 128 + w * 16 + l15;

    const unsigned short* wp = Whb + (size_t)col * DLAT + l4 * 8;
    const float bias = bh[col];
    const int myrow = b0 + l4 * 4;    // first of this lane's 4 output rows

    // xi for t=0
    float xc[4];
    #pragma unroll
    for (int i = 0; i < 4; ++i)
        xc[i] = hs[(size_t)(myrow + i) * DLAT + col];

    for (int t = 0; t < SEQ; ++t) {
        // prefetch xi for t+1 (HBM latency hides under spin + K-loop)
        float nx[4];
        if (t + 1 < SEQ) {
            const float* xp = hs + (size_t)(t + 1) * BATCH * DLAT;
            #pragma unroll
            for (int i = 0; i < 4; ++i)
                nx[i] = xp[(size_t)(myrow + i) * DLAT + col];
        }

        f32x4 acc0 = (f32x4)0.f, acc1 = (f32x4)0.f;
        const int cur = t & 1;

        if (t > 0) {
            // ---- bg-local barrier: all 64 same-bg waves must have flag >= t
            const unsigned tgt = (unsigned)t;
            const unsigned int* fp = flags + bg * 64 + lane;
            for (;;) {
                unsigned f = __hip_atomic_load(fp, __ATOMIC_ACQUIRE,
                                               __HIP_MEMORY_SCOPE_AGENT);
                if (__all((int)(f >= tgt))) break;
            }

            // ---- stage h_prev 32 KB: hbuf[(t+1)&1] -> tile[cur] (swizzled)
            const u64* src = (const u64*)hbuf
                           + ((size_t)((t + 1) & 1) * BATCH + b0) * (DLAT / 4);
            u64 q[8];
            #pragma unroll
            for (int p = 0; p < 4; ++p) {
                const int c = p * 512 + tid;          // 16B chunk id, 0..2047
                const size_t si = (size_t)(c >> 7) * 256 + (c & 127) * 2;
                q[p * 2]     = __hip_atomic_load(src + si,     __ATOMIC_RELAXED, __HIP_MEMORY_SCOPE_AGENT);
                q[p * 2 + 1] = __hip_atomic_load(src + si + 1, __ATOMIC_RELAXED, __HIP_MEMORY_SCOPE_AGENT);
            }
            char* tb = (char*)tile[cur];
            #pragma unroll
            for (int p = 0; p < 4; ++p) {
                const int c  = p * 512 + tid;
                const int r  = c >> 7;                // row 0..15
                const int kb = (c & 127) * 16;        // byte within row
                union { u64 qq[2]; bf16x8 v; } u;
                u.qq[0] = q[p * 2]; u.qq[1] = q[p * 2 + 1];
                *(bf16x8*)(tb + r * 2048 + (kb ^ ((r & 7) << 4))) = u.v;
            }
            __syncthreads();

            // ---- K-loop: A from swizzled LDS, W streamed from L2
            const char* ta = (const char*)tile[cur] + l15 * 2048;
            const int swz = (l15 & 7) << 4;
            #pragma unroll
            for (int kk = 0; kk < 32; kk += 2) {
                bf16x8 a0 = *(const bf16x8*)(ta + ((kk * 64 + l4 * 16) ^ swz));
                bf16x8 a1 = *(const bf16x8*)(ta + (((kk + 1) * 64 + l4 * 16) ^ swz));
                bf16x8 w0 = *(const bf16x8*)(wp + kk * 32);
                bf16x8 w1 = *(const bf16x8*)(wp + (kk + 1) * 32);
                acc0 = __builtin_amdgcn_mfma_f32_16x16x32_bf16(a0, w0, acc0, 0, 0, 0);
                acc1 = __builtin_amdgcn_mfma_f32_16x16x32_bf16(a1, w1, acc1, 0, 0, 0);
            }
        }

        // ---- epilogue: tanh, write hs (f32) + hbuf (bf16, agent scope)
        float* hsw = hs + (size_t)t * BATCH * DLAT;
        unsigned short* hbw = hbuf + (size_t)cur * BATCH * DLAT;
        #pragma unroll
        for (int i = 0; i < 4; ++i) {
            const size_t row = (size_t)(myrow + i);
            float v = acc0[i] + acc1[i] + xc[i] + bias;
            v = fminf(fmaxf(v, -15.f), 15.f);
            float e = __expf(2.f * v);
            float h = 1.f - 2.f * __builtin_amdgcn_rcpf(e + 1.f);   // tanh(v)
            hsw[row * DLAT + col] = h;
            __hip_atomic_store(hbw + row * DLAT + col, f2bf(h),
                               __ATOMIC_RELAXED, __HIP_MEMORY_SCOPE_AGENT);
            if (t == SEQ - 1) hfin[row * DLAT + col] = h;
        }

        // ---- release: this wave's step t complete
        if (lane == 0)
            __hip_atomic_store(flags + bg * 64 + cg * 8 + w, (unsigned)(t + 1),
                               __ATOMIC_RELEASE, __HIP_MEMORY_SCOPE_AGENT);

        #pragma unroll
        for (int i = 0; i < 4; ++i) xc[i] = nx[i];
    }
}

extern "C" void kernel_launch(void* const* d_in, const int* in_sizes, int n_in,
                              void* d_out, int out_size, void* d_ws, size_t ws_size,
                              hipStream_t stream) {
    const float* x  = (const float*)d_in[0];
    const float* Wi = (const float*)d_in[1];
    const float* Wh = (const float*)d_in[2];
    const float* bh = (const float*)d_in[3];

    float* out  = (float*)d_out;
    float* hfin = out;                                  // [BATCH, DLAT]
    float* hs   = out + (size_t)BATCH * DLAT;           // [SEQ, BATCH, DLAT]

    unsigned int*   flags = (unsigned int*)d_ws;                          // 4 KB
    unsigned short* Wib   = (unsigned short*)((char*)d_ws + 4096);        // 1 MB
    unsigned short* Whb   = Wib + (size_t)DLAT * DIN;                     // 2 MB
    unsigned short* hbuf  = Whb + (size_t)DLAT * DLAT;                    // 1 MB

    convert_weights<<<512, 256, 0, stream>>>(Wi, Wh, Wib, Whb, flags);

    const int M = SEQ * BATCH;
    xproj_kernel<<<(M / 64) * (DLAT / 256), 1024, 0, stream>>>(x, Wib, hs);

    rnn_scan<<<NBG * NCG, 512, 0, stream>>>(Whb, bh, hs, hfin, hbuf, flags);
}

// Round 6
// 8928.844 us; speedup vs baseline: 3.0035x; 3.0035x over previous
//
#include <hip/hip_runtime.h>
#include <hip/hip_bf16.h>

#define SEQ   512
#define BATCH 256
#define DIN   512
#define DLAT  1024

#define NBG   16                 // batch groups of 16 rows
#define NCG   8                  // col groups of 128 cols
#define NFLAGS (NBG * NCG)       // one flag per block

typedef __attribute__((ext_vector_type(8))) short bf16x8;
typedef __attribute__((ext_vector_type(4))) float f32x4;
typedef unsigned long long u64;

__device__ __forceinline__ unsigned short f2bf(float f) {
    union { float f; unsigned u; } v; v.f = f;
    unsigned r = v.u + 0x7FFFu + ((v.u >> 16) & 1u);   // RNE
    return (unsigned short)(r >> 16);
}

__global__ void convert_weights(const float* __restrict__ Wi, const float* __restrict__ Wh,
                                unsigned short* __restrict__ Wib, unsigned short* __restrict__ Whb,
                                unsigned int* __restrict__ flags) {
    const int nWi = DLAT * DIN;
    const int nWh = DLAT * DLAT;
    const int t0 = blockIdx.x * blockDim.x + threadIdx.x;
    if (t0 < NFLAGS) flags[t0] = 0;
    for (int idx = t0; idx < nWi + nWh; idx += gridDim.x * blockDim.x) {
        if (idx < nWi) Wib[idx] = f2bf(Wi[idx]);
        else           Whb[idx - nWi] = f2bf(Wh[idx - nWi]);
    }
}

// Phase 1: xi = x @ Wi^T. (validated rounds 1-5)
__global__ __launch_bounds__(1024) void xproj_kernel(const float* __restrict__ x,
                                                     const unsigned short* __restrict__ Wib,
                                                     float* __restrict__ xi) {
    const int tid  = threadIdx.x;
    const int lane = tid & 63;
    const int w    = tid >> 6;
    const int l15  = lane & 15;
    const int l4   = lane >> 4;
    const int mblk = blockIdx.x >> 2;
    const int nblk = blockIdx.x & 3;
    const size_t m0 = (size_t)mblk * 64 + (w & 3) * 16;
    const int    n0 = nblk * 256 + (w >> 2) * 64;

    const float* xp = x + (m0 + l15) * DIN + l4 * 8;

    f32x4 acc[4];
    #pragma unroll
    for (int j = 0; j < 4; ++j) acc[j] = (f32x4)0.f;

    const unsigned short* bp[4];
    #pragma unroll
    for (int j = 0; j < 4; ++j)
        bp[j] = Wib + (size_t)(n0 + j * 16 + l15) * DIN + l4 * 8;

    #pragma unroll 4
    for (int kc = 0; kc < DIN / 32; ++kc) {
        f32x4 a0 = *(const f32x4*)(xp + kc * 32);
        f32x4 a1 = *(const f32x4*)(xp + kc * 32 + 4);
        bf16x8 af;
        #pragma unroll
        for (int i = 0; i < 4; ++i) { af[i] = (short)f2bf(a0[i]); af[i + 4] = (short)f2bf(a1[i]); }
        #pragma unroll
        for (int j = 0; j < 4; ++j) {
            bf16x8 bf = *(const bf16x8*)(bp[j] + kc * 32);
            acc[j] = __builtin_amdgcn_mfma_f32_16x16x32_bf16(af, bf, acc[j], 0, 0, 0);
        }
    }
    #pragma unroll
    for (int j = 0; j < 4; ++j) {
        const int col = n0 + j * 16 + l15;
        #pragma unroll
        for (int i = 0; i < 4; ++i)
            xi[(m0 + l4 * 4 + i) * DLAT + col] = acc[j][i];
    }
}

// Phase 2: 128 blocks = 16 bg x 8 cg, 512 thr (8 waves, 16 cols each).
// Classical fence protocol, one release + one acquire per block per step:
//   producer: plain hbuf stores -> __syncthreads (per-wave vmcnt drain -> L2)
//             -> tid0: fence(release,agent) [wbl2+wait] -> relaxed sc1 flag store
//   consumer: wave0 spins on relaxed sc1 flags -> fence(acquire,agent)
//             [buffer_inv] -> __syncthreads -> plain staging loads (fresh).
// Streaming f32 (xi in, hs out) nontemporal to keep L2 nearly clean.
__global__ __launch_bounds__(512, 1) void rnn_scan(
        const unsigned short* __restrict__ Whb,
        const float* __restrict__ bh,
        float* __restrict__ hs,                 // xi on entry; overwritten with h
        float* __restrict__ hfin,
        unsigned short* __restrict__ hbuf,      // [2][BATCH][DLAT] bf16
        unsigned int* __restrict__ flags) {     // [NBG][NCG] monotone counters
    __shared__ unsigned short tile[2][16][1024];   // 64 KB, rows XOR-swizzled

    const int tid  = threadIdx.x;
    const int lane = tid & 63;
    const int w    = tid >> 6;        // 0..7
    const int l15  = lane & 15;
    const int l4   = lane >> 4;       // 0..3
    const int bg   = blockIdx.x >> 3; // 0..15
    const int cg   = blockIdx.x & 7;  // 0..7
    const int b0   = bg * 16;
    const int col  = cg * 128 + w * 16 + l15;

    const unsigned short* wp = Whb + (size_t)col * DLAT + l4 * 8;
    const float bias = bh[col];
    const int myrow = b0 + l4 * 4;    // first of this lane's 4 output rows

    // xi for t=0 (nontemporal: no reuse, keep L2 clean)
    float xc[4];
    #pragma unroll
    for (int i = 0; i < 4; ++i)
        xc[i] = __builtin_nontemporal_load(hs + (size_t)(myrow + i) * DLAT + col);

    for (int t = 0; t < SEQ; ++t) {
        // prefetch xi for t+1 (latency hides under spin + stage + K-loop)
        float nx[4];
        if (t + 1 < SEQ) {
            const float* xp = hs + (size_t)(t + 1) * BATCH * DLAT;
            #pragma unroll
            for (int i = 0; i < 4; ++i)
                nx[i] = __builtin_nontemporal_load(xp + (size_t)(myrow + i) * DLAT + col);
        }

        f32x4 acc0 = (f32x4)0.f, acc1 = (f32x4)0.f;
        const int cur = t & 1;

        if (t > 0) {
            // ---- consumer sync: wave0 spins, then ONE acquire fence ----
            if (w == 0) {
                const unsigned tgt = (unsigned)t;
                const unsigned int* fp = flags + bg * NCG + (lane & 7);
                for (;;) {
                    unsigned f = __hip_atomic_load(fp, __ATOMIC_RELAXED,
                                                   __HIP_MEMORY_SCOPE_AGENT);
                    int ok = (lane < 8) ? (int)(f >= tgt) : 1;
                    if (__all(ok)) break;
                }
                __builtin_amdgcn_fence(__ATOMIC_ACQUIRE, "agent");  // buffer_inv
            }
            __syncthreads();   // bar1: inv done & flags confirmed, all waves

            // ---- stage h_prev 32 KB: hbuf[(t+1)&1] -> tile[cur] (swizzled)
            const char* srcb = (const char*)hbuf
                             + ((size_t)((t + 1) & 1) * BATCH + b0) * DLAT * 2;
            char* tb = (char*)tile[cur];
            #pragma unroll
            for (int p = 0; p < 4; ++p) {
                const int c = p * 512 + tid;          // 16B chunk id, 0..2047
                bf16x8 v = *(const bf16x8*)(srcb + c * 16);     // plain load
                const int r  = c >> 7;                // row 0..15
                const int kb = (c & 127) * 16;        // byte within row
                *(bf16x8*)(tb + r * 2048 + (kb ^ ((r & 7) << 4))) = v;
            }
            __syncthreads();   // bar2: tile[cur] ready

            // ---- K-loop: A from swizzled LDS, W streamed from L2/MALL
            const char* ta = (const char*)tile[cur] + l15 * 2048;
            const int swz = (l15 & 7) << 4;
            #pragma unroll
            for (int kk = 0; kk < 32; kk += 2) {
                bf16x8 a0 = *(const bf16x8*)(ta + ((kk * 64 + l4 * 16) ^ swz));
                bf16x8 a1 = *(const bf16x8*)(ta + (((kk + 1) * 64 + l4 * 16) ^ swz));
                bf16x8 w0 = *(const bf16x8*)(wp + kk * 32);
                bf16x8 w1 = *(const bf16x8*)(wp + (kk + 1) * 32);
                acc0 = __builtin_amdgcn_mfma_f32_16x16x32_bf16(a0, w0, acc0, 0, 0, 0);
                acc1 = __builtin_amdgcn_mfma_f32_16x16x32_bf16(a1, w1, acc1, 0, 0, 0);
            }
        } else {
            __syncthreads();   // keep per-step barrier structure uniform
        }

        // ---- epilogue: tanh, nt-store hs (f32), plain store hbuf (bf16)
        float* hsw = hs + (size_t)t * BATCH * DLAT;
        unsigned short* hbw = hbuf + (size_t)cur * BATCH * DLAT;
        #pragma unroll
        for (int i = 0; i < 4; ++i) {
            const size_t row = (size_t)(myrow + i);
            float v = acc0[i] + acc1[i] + xc[i] + bias;
            v = fminf(fmaxf(v, -15.f), 15.f);
            float e = __expf(2.f * v);
            float h = 1.f - 2.f * __builtin_amdgcn_rcpf(e + 1.f);   // tanh(v)
            __builtin_nontemporal_store(h, hsw + row * DLAT + col);
            hbw[row * DLAT + col] = f2bf(h);                        // plain
            if (t == SEQ - 1)
                __builtin_nontemporal_store(h, hfin + row * DLAT + col);
        }

        // bar3: every wave's stores are at least in L2 (vmcnt drain)
        __syncthreads();
        // ---- producer sync: ONE release fence (wbl2+wait), then flag ----
        if (tid == 0 && t + 1 < SEQ) {
            __builtin_amdgcn_fence(__ATOMIC_RELEASE, "agent");  // wbl2 sc1 + wait
            __hip_atomic_store(flags + bg * NCG + cg, (unsigned)(t + 1),
                               __ATOMIC_RELAXED, __HIP_MEMORY_SCOPE_AGENT);
        }

        #pragma unroll
        for (int i = 0; i < 4; ++i) xc[i] = nx[i];
    }
}

extern "C" void kernel_launch(void* const* d_in, const int* in_sizes, int n_in,
                              void* d_out, int out_size, void* d_ws, size_t ws_size,
                              hipStream_t stream) {
    const float* x  = (const float*)d_in[0];
    const float* Wi = (const float*)d_in[1];
    const float* Wh = (const float*)d_in[2];
    const float* bh = (const float*)d_in[3];

    float* out  = (float*)d_out;
    float* hfin = out;                                  // [BATCH, DLAT]
    float* hs   = out + (size_t)BATCH * DLAT;           // [SEQ, BATCH, DLAT]

    unsigned int*   flags = (unsigned int*)d_ws;                          // 512 B
    unsigned short* Wib   = (unsigned short*)((char*)d_ws + 4096);        // 1 MB
    unsigned short* Whb   = Wib + (size_t)DLAT * DIN;                     // 2 MB
    unsigned short* hbuf  = Whb + (size_t)DLAT * DLAT;                    // 1 MB

    convert_weights<<<512, 256, 0, stream>>>(Wi, Wh, Wib, Whb, flags);

    const int M = SEQ * BATCH;
    xproj_kernel<<<(M / 64) * (DLAT / 256), 1024, 0, stream>>>(x, Wib, hs);

    rnn_scan<<<NBG * NCG, 512, 0, stream>>>(Whb, bh, hs, hfin, hbuf, flags);
}

// Round 8
// 8185.162 us; speedup vs baseline: 3.2764x; 1.0909x over previous
//
#include <hip/hip_runtime.h>
#include <hip/hip_bf16.h>

#define SEQ   512
#define BATCH 256
#define DIN   512
#define DLAT  1024

#define NBG    16                // batch groups of 16 rows
#define NCB    16                // blocks per bg, 64 cols each
#define NFLAGS (NBG * NCB)       // 256, one per block
#define KK_LDS 24                // k-chunks of W in LDS (of 32); rest in regs

typedef __attribute__((ext_vector_type(8))) short bf16x8;
typedef __attribute__((ext_vector_type(4))) float f32x4;
typedef unsigned long long u64;

__device__ __forceinline__ unsigned short f2bf(float f) {
    union { float f; unsigned u; } v; v.f = f;
    unsigned r = v.u + 0x7FFFu + ((v.u >> 16) & 1u);   // RNE
    return (unsigned short)(r >> 16);
}

__global__ void convert_weights(const float* __restrict__ Wi, const float* __restrict__ Wh,
                                unsigned short* __restrict__ Wib, unsigned short* __restrict__ Whb,
                                unsigned int* __restrict__ flags) {
    const int nWi = DLAT * DIN;
    const int nWh = DLAT * DLAT;
    const int t0 = blockIdx.x * blockDim.x + threadIdx.x;
    if (t0 < NFLAGS) flags[t0] = 0;
    for (int idx = t0; idx < nWi + nWh; idx += gridDim.x * blockDim.x) {
        if (idx < nWi) Wib[idx] = f2bf(Wi[idx]);
        else           Whb[idx - nWi] = f2bf(Wh[idx - nWi]);
    }
}

// Phase 1: xi = x @ Wi^T. (validated rounds 1-7)
__global__ __launch_bounds__(1024) void xproj_kernel(const float* __restrict__ x,
                                                     const unsigned short* __restrict__ Wib,
                                                     float* __restrict__ xi) {
    const int tid  = threadIdx.x;
    const int lane = tid & 63;
    const int w    = tid >> 6;
    const int l15  = lane & 15;
    const int l4   = lane >> 4;
    const int mblk = blockIdx.x >> 2;
    const int nblk = blockIdx.x & 3;
    const size_t m0 = (size_t)mblk * 64 + (w & 3) * 16;
    const int    n0 = nblk * 256 + (w >> 2) * 64;

    const float* xp = x + (m0 + l15) * DIN + l4 * 8;

    f32x4 acc[4];
    #pragma unroll
    for (int j = 0; j < 4; ++j) acc[j] = (f32x4)0.f;

    const unsigned short* bp[4];
    #pragma unroll
    for (int j = 0; j < 4; ++j)
        bp[j] = Wib + (size_t)(n0 + j * 16 + l15) * DIN + l4 * 8;

    #pragma unroll 4
    for (int kc = 0; kc < DIN / 32; ++kc) {
        f32x4 a0 = *(const f32x4*)(xp + kc * 32);
        f32x4 a1 = *(const f32x4*)(xp + kc * 32 + 4);
        bf16x8 af;
        #pragma unroll
        for (int i = 0; i < 4; ++i) { af[i] = (short)f2bf(a0[i]); af[i + 4] = (short)f2bf(a1[i]); }
        #pragma unroll
        for (int j = 0; j < 4; ++j) {
            bf16x8 bf = *(const bf16x8*)(bp[j] + kc * 32);
            acc[j] = __builtin_amdgcn_mfma_f32_16x16x32_bf16(af, bf, acc[j], 0, 0, 0);
        }
    }
    #pragma unroll
    for (int j = 0; j < 4; ++j) {
        const int col = n0 + j * 16 + l15;
        #pragma unroll
        for (int i = 0; i < 4; ++i)
            xi[(m0 + l4 * 4 + i) * DLAT + col] = acc[j][i];
    }
}

// Phase 2: 256 blocks = 16 bg x 16 col-blocks (64 cols), 256 thr (4 waves,
// 16 cols each), 1 block/CU (128 KiB LDS).
// Sync protocol = round 6's PROVEN fence pair, once per block per step:
//   producer: plain hbuf stores -> __syncthreads (vmcnt drain -> L2) ->
//             tid0: fence(release,agent) [wbl2] -> relaxed sc1 flag store.
//   consumer: wave0 relaxed-spin on 16 same-bg flags -> fence(acquire,agent)
//             [buffer_inv] -> __syncthreads -> plain staging loads.
// W_h: 24/32 k-chunks in LDS (per-wave region, filled once), 8 in VGPRs ->
// the per-step buffer_inv has no W_h to evict (round 6's hidden cost).
// MFMA operands swapped (W as A, h as B) -> acc holds h^T: each lane owns
// 4 consecutive out-cols of one batch row -> f32x4 NT I/O, u64 hbuf store.
__global__ __launch_bounds__(256, 1) void rnn_scan(
        const unsigned short* __restrict__ Whb,
        const float* __restrict__ bh,
        float* __restrict__ hs,                 // xi on entry; overwritten with h
        float* __restrict__ hfin,
        unsigned short* __restrict__ hbuf,      // [2][BATCH][DLAT] bf16
        unsigned int* __restrict__ flags) {     // [NBG][NCB] monotone counters
    __shared__ __align__(16) unsigned short hT[16][1024];          // 32 KB
    __shared__ __align__(16) unsigned short wl[4][KK_LDS][512];    // 96 KB

    const int tid  = threadIdx.x;
    const int lane = tid & 63;
    const int w    = tid >> 6;        // 0..3
    const int l15  = lane & 15;
    const int l4   = lane >> 4;       // 0..3
    const int bg   = blockIdx.x >> 4; // 0..15
    const int cbk  = blockIdx.x & 15; // 0..15
    const int b0   = bg * 16;
    const int colf = cbk * 64 + w * 16;     // wave's 16-col tile base

    // ---- W fill: LDS part (each wave its own region) ----
    #pragma unroll
    for (int kk = 0; kk < KK_LDS; ++kk)
        *(bf16x8*)&wl[w][kk][lane * 8] =
            *(const bf16x8*)(Whb + (size_t)(colf + l15) * DLAT + kk * 32 + l4 * 8);
    // ---- W tail: 8 k-chunks in registers ----
    bf16x8 wreg[8];
    #pragma unroll
    for (int r = 0; r < 8; ++r)
        wreg[r] = *(const bf16x8*)(Whb + (size_t)(colf + l15) * DLAT
                                   + (KK_LDS + r) * 32 + l4 * 8);

    const f32x4 bias = *(const f32x4*)(bh + colf + l4 * 4);
    const int rowb = b0 + l15;            // this lane's batch row
    const int colb = colf + l4 * 4;       // this lane's first out-col

    // xi for t=0 (NT: streaming, keep L2 clean)
    f32x4 xiv = __builtin_nontemporal_load(
        (const f32x4*)(hs + (size_t)rowb * DLAT + colb));

    for (int t = 0; t < SEQ; ++t) {
        // prefetch xi for t+1 (latency hides under spin + stage + K-loop)
        f32x4 nx = (f32x4)0.f;
        if (t + 1 < SEQ)
            nx = __builtin_nontemporal_load(
                (const f32x4*)(hs + ((size_t)(t + 1) * BATCH + rowb) * DLAT + colb));

        const int cur = t & 1;
        f32x4 acc0 = (f32x4)0.f, acc1 = (f32x4)0.f;

        if (t > 0) {
            // ---- consumer sync: wave0 spin, then ONE acquire fence ----
            if (w == 0) {
                const unsigned tgt = (unsigned)t;
                const unsigned int* fp = flags + bg * NCB + l15;
                for (;;) {
                    unsigned f = __hip_atomic_load(fp, __ATOMIC_RELAXED,
                                                   __HIP_MEMORY_SCOPE_AGENT);
                    if (__all((int)(f >= tgt))) break;
                }
                __builtin_amdgcn_fence(__ATOMIC_ACQUIRE, "agent");  // buffer_inv
            }
            __syncthreads();   // bar1: inv done, flags confirmed, all waves

            // ---- stage h_prev 32 KB: hbuf[(t+1)&1] -> hT (plain, swizzled)
            const char* srcb = (const char*)hbuf
                             + ((size_t)((t + 1) & 1) * BATCH + b0) * DLAT * 2;
            char* tb = (char*)hT;
            #pragma unroll
            for (int p = 0; p < 8; ++p) {
                const int c  = p * 256 + tid;         // 16B chunk id, 0..2047
                bf16x8 v = *(const bf16x8*)(srcb + c * 16);
                const int r  = c >> 7;
                const int kb = (c & 127) * 16;
                *(bf16x8*)(tb + r * 2048 + (kb ^ ((r & 7) << 4))) = v;
            }
            __syncthreads();   // bar2: hT ready

            // ---- K-loop: A = W (LDS/regs), B = h (LDS, swizzled) ----
            const char* ta = (const char*)hT + l15 * 2048;
            const int sw = (l15 & 7) << 4;
            #pragma unroll
            for (int kk = 0; kk < KK_LDS; kk += 2) {
                bf16x8 h0 = *(const bf16x8*)(ta + ((kk * 64 + l4 * 16) ^ sw));
                bf16x8 h1 = *(const bf16x8*)(ta + (((kk + 1) * 64 + l4 * 16) ^ sw));
                bf16x8 w0 = *(const bf16x8*)&wl[w][kk][lane * 8];
                bf16x8 w1 = *(const bf16x8*)&wl[w][kk + 1][lane * 8];
                acc0 = __builtin_amdgcn_mfma_f32_16x16x32_bf16(w0, h0, acc0, 0, 0, 0);
                acc1 = __builtin_amdgcn_mfma_f32_16x16x32_bf16(w1, h1, acc1, 0, 0, 0);
            }
            #pragma unroll
            for (int r = 0; r < 8; r += 2) {
                const int kk = KK_LDS + r;
                bf16x8 h0 = *(const bf16x8*)(ta + ((kk * 64 + l4 * 16) ^ sw));
                bf16x8 h1 = *(const bf16x8*)(ta + (((kk + 1) * 64 + l4 * 16) ^ sw));
                acc0 = __builtin_amdgcn_mfma_f32_16x16x32_bf16(wreg[r],     h0, acc0, 0, 0, 0);
                acc1 = __builtin_amdgcn_mfma_f32_16x16x32_bf16(wreg[r + 1], h1, acc1, 0, 0, 0);
            }
        } else {
            __syncthreads();   // keep per-step structure uniform at t=0
        }

        // ---- epilogue: tanh; NT f32x4 hs store; plain u64 hbuf store ----
        f32x4 ho;
        #pragma unroll
        for (int i = 0; i < 4; ++i) {
            float v = acc0[i] + acc1[i] + xiv[i] + bias[i];
            v = fminf(fmaxf(v, -15.f), 15.f);
            float e = __expf(2.f * v);
            ho[i] = 1.f - 2.f * __builtin_amdgcn_rcpf(e + 1.f);   // tanh(v)
        }
        __builtin_nontemporal_store(ho,
            (f32x4*)(hs + ((size_t)t * BATCH + rowb) * DLAT + colb));
        u64 pk =  (u64)f2bf(ho[0])        | ((u64)f2bf(ho[1]) << 16)
               | ((u64)f2bf(ho[2]) << 32) | ((u64)f2bf(ho[3]) << 48);
        *(u64*)(hbuf + ((size_t)cur * BATCH + rowb) * DLAT + colb) = pk;
        if (t == SEQ - 1)
            __builtin_nontemporal_store(ho,
                (f32x4*)(hfin + (size_t)rowb * DLAT + colb));

        // bar3: every wave's stores are at least in L2 (vmcnt drain)
        __syncthreads();
        // ---- producer sync: ONE release fence (wbl2), then flag ----
        if (tid == 0 && t + 1 < SEQ) {
            __builtin_amdgcn_fence(__ATOMIC_RELEASE, "agent");  // wbl2 + wait
            __hip_atomic_store(flags + bg * NCB + cbk, (unsigned)(t + 1),
                               __ATOMIC_RELAXED, __HIP_MEMORY_SCOPE_AGENT);
        }

        xiv = nx;
    }
}

extern "C" void kernel_launch(void* const* d_in, const int* in_sizes, int n_in,
                              void* d_out, int out_size, void* d_ws, size_t ws_size,
                              hipStream_t stream) {
    const float* x  = (const float*)d_in[0];
    const float* Wi = (const float*)d_in[1];
    const float* Wh = (const float*)d_in[2];
    const float* bh = (const float*)d_in[3];

    float* out  = (float*)d_out;
    float* hfin = out;                                  // [BATCH, DLAT]
    float* hs   = out + (size_t)BATCH * DLAT;           // [SEQ, BATCH, DLAT]

    unsigned int*   flags = (unsigned int*)d_ws;                          // 1 KB
    unsigned short* Wib   = (unsigned short*)((char*)d_ws + 4096);        // 1 MB
    unsigned short* Whb   = Wib + (size_t)DLAT * DIN;                     // 2 MB
    unsigned short* hbuf  = Whb + (size_t)DLAT * DLAT;                    // 1 MB

    convert_weights<<<512, 256, 0, stream>>>(Wi, Wh, Wib, Whb, flags);

    const int M = SEQ * BATCH;
    xproj_kernel<<<(M / 64) * (DLAT / 256), 1024, 0, stream>>>(x, Wib, hs);

    rnn_scan<<<NBG * NCB, 256, 0, stream>>>(Whb, bh, hs, hfin, hbuf, flags);
}

// Round 10
// 3037.937 us; speedup vs baseline: 8.8277x; 2.6943x over previous
//
#include <hip/hip_runtime.h>
#include <hip/hip_bf16.h>

#define SEQ   512
#define BATCH 256
#define DIN   512
#define DLAT  1024

#define NBG    16                // batch groups of 16 rows
#define NCB    16                // blocks per bg, 64 cols each
#define NBLK   (NBG * NCB)       // 256
#define KK_LDS 24                // k-chunks of W in LDS (of 32); rest in regs

// flags u32 layout (each slot on its own 128B line):
//   [0]              g_total     (startup arrival, RMW only)
//   [32*(1+x)]       startcnt[x] (blocks on XCD x, RMW only)
//   [32*(9+x)]       cnt[x]      (per-step arrival, RMW only)
//   [32*(17+x)]      xstep[x]    (plain store + wbl2; sc1-load readers)
#define F_GTOT  0
#define F_SCNT(x) (32 * (1 + (x)))
#define F_CNT(x)  (32 * (9 + (x)))
#define F_XSTEP(x)(32 * (17 + (x)))
#define F_ZERO  800

typedef __attribute__((ext_vector_type(8))) short bf16x8;
typedef __attribute__((ext_vector_type(4))) float f32x4;
typedef __attribute__((ext_vector_type(4))) unsigned int u32x4;
typedef unsigned long long u64;

__device__ __forceinline__ unsigned short f2bf(float f) {
    union { float f; unsigned u; } v; v.f = f;
    unsigned r = v.u + 0x7FFFu + ((v.u >> 16) & 1u);   // RNE
    return (unsigned short)(r >> 16);
}

__global__ void convert_weights(const float* __restrict__ Wi, const float* __restrict__ Wh,
                                unsigned short* __restrict__ Wib, unsigned short* __restrict__ Whb,
                                unsigned int* __restrict__ flags) {
    const int nWi = DLAT * DIN;
    const int nWh = DLAT * DLAT;
    const int t0 = blockIdx.x * blockDim.x + threadIdx.x;
    if (t0 < F_ZERO) flags[t0] = 0;
    for (int idx = t0; idx < nWi + nWh; idx += gridDim.x * blockDim.x) {
        if (idx < nWi) Wib[idx] = f2bf(Wi[idx]);
        else           Whb[idx - nWi] = f2bf(Wh[idx - nWi]);
    }
}

// Phase 1: xi = x @ Wi^T. (validated rounds 1-8)
__global__ __launch_bounds__(1024) void xproj_kernel(const float* __restrict__ x,
                                                     const unsigned short* __restrict__ Wib,
                                                     float* __restrict__ xi) {
    const int tid  = threadIdx.x;
    const int lane = tid & 63;
    const int w    = tid >> 6;
    const int l15  = lane & 15;
    const int l4   = lane >> 4;
    const int mblk = blockIdx.x >> 2;
    const int nblk = blockIdx.x & 3;
    const size_t m0 = (size_t)mblk * 64 + (w & 3) * 16;
    const int    n0 = nblk * 256 + (w >> 2) * 64;

    const float* xp = x + (m0 + l15) * DIN + l4 * 8;

    f32x4 acc[4];
    #pragma unroll
    for (int j = 0; j < 4; ++j) acc[j] = (f32x4)0.f;

    const unsigned short* bp[4];
    #pragma unroll
    for (int j = 0; j < 4; ++j)
        bp[j] = Wib + (size_t)(n0 + j * 16 + l15) * DIN + l4 * 8;

    #pragma unroll 4
    for (int kc = 0; kc < DIN / 32; ++kc) {
        f32x4 a0 = *(const f32x4*)(xp + kc * 32);
        f32x4 a1 = *(const f32x4*)(xp + kc * 32 + 4);
        bf16x8 af;
        #pragma unroll
        for (int i = 0; i < 4; ++i) { af[i] = (short)f2bf(a0[i]); af[i + 4] = (short)f2bf(a1[i]); }
        #pragma unroll
        for (int j = 0; j < 4; ++j) {
            bf16x8 bf = *(const bf16x8*)(bp[j] + kc * 32);
            acc[j] = __builtin_amdgcn_mfma_f32_16x16x32_bf16(af, bf, acc[j], 0, 0, 0);
        }
    }
    #pragma unroll
    for (int j = 0; j < 4; ++j) {
        const int col = n0 + j * 16 + l15;
        #pragma unroll
        for (int i = 0; i < 4; ++i)
            xi[(m0 + l4 * 4 + i) * DLAT + col] = acc[j][i];
    }
}

// Phase 2: 256 blocks, 256 thr (4 waves), 1 block/CU (128 KiB LDS).
// gfx950 coherence model (established r5-r9): ALL stores/RMWs land dirty in
// the local XCD L2; only wbl2 pushes them to MALL; sc1 loads read MALL;
// RMW-written data may only be read by RMWs.
// Protocol (elected per-XCD flusher, 2 wbl2/XCD/step instead of 32+32 fence
// pairs): every block tid0 RMW-bumps cnt[xcd] after bar3 (its data is in L2
// by the vmcnt drain); the LAST arriver of the XCD does
//   fence(release) [wbl2: ALL same-XCD blocks' hbuf -> MALL]
//   xstep[xcd] = t+1 (plain)
//   fence(release) [wbl2: flag -> MALL].
// Consumers: wave0 spins on xstep[0..7] (active XCDs) via sc1 loads; staging
// reads hbuf via sc1 loads. No inv anywhere. Global lockstep.
__global__ __launch_bounds__(256, 1) void rnn_scan(
        const unsigned short* __restrict__ Whb,
        const float* __restrict__ bh,
        float* __restrict__ hs,                 // xi on entry; overwritten with h
        float* __restrict__ hfin,
        unsigned short* __restrict__ hbuf,      // [2][BATCH][DLAT] bf16
        unsigned int* __restrict__ flags) {
    __shared__ __align__(16) unsigned short hT[16][1024];          // 32 KB
    __shared__ __align__(16) unsigned short wl[4][KK_LDS][512];    // 96 KB
    __shared__ unsigned amask_s;

    const int tid  = threadIdx.x;
    const int lane = tid & 63;
    const int w    = tid >> 6;        // 0..3
    const int l15  = lane & 15;
    const int l4   = lane >> 4;       // 0..3
    const int bid  = blockIdx.x;
    const int bg   = bid & 15;        // 0..15
    const int cbk  = bid >> 4;        // 0..15
    const int b0   = bg * 16;
    const int colf = cbk * 64 + w * 16;     // wave's 16-col tile base

    // ---- W fill: LDS part (each wave its own region) ----
    #pragma unroll
    for (int kk = 0; kk < KK_LDS; ++kk)
        *(bf16x8*)&wl[w][kk][lane * 8] =
            *(const bf16x8*)(Whb + (size_t)(colf + l15) * DLAT + kk * 32 + l4 * 8);
    // ---- W tail: 8 k-chunks in registers ----
    bf16x8 wreg[8];
    #pragma unroll
    for (int r = 0; r < 8; ++r)
        wreg[r] = *(const bf16x8*)(Whb + (size_t)(colf + l15) * DLAT
                                   + (KK_LDS + r) * 32 + l4 * 8);

    // ---- startup census: who is on which XCD? (RMW-only, rule-consistent) ----
    unsigned xcd = 0, nbx = 0;
    if (tid == 0) {
        asm volatile("s_getreg_b32 %0, hwreg(HW_REG_XCC_ID)" : "=s"(xcd));
        xcd &= 7;
        __hip_atomic_fetch_add(flags + F_SCNT(xcd), 1u, __ATOMIC_RELAXED,
                               __HIP_MEMORY_SCOPE_AGENT);
        __hip_atomic_fetch_add(flags + F_GTOT, 1u, __ATOMIC_RELAXED,
                               __HIP_MEMORY_SCOPE_AGENT);
        // RMW-spin (coherent by atomicity), with backoff
        while (__hip_atomic_fetch_add(flags + F_GTOT, 0u, __ATOMIC_RELAXED,
                                      __HIP_MEMORY_SCOPE_AGENT) < NBLK)
            __builtin_amdgcn_s_sleep(32);
        unsigned am = 0;
        #pragma unroll
        for (int x2 = 0; x2 < 8; ++x2) {
            unsigned c = __hip_atomic_fetch_add(flags + F_SCNT(x2), 0u,
                                                __ATOMIC_RELAXED, __HIP_MEMORY_SCOPE_AGENT);
            if (c) am |= 1u << x2;
            if (x2 == (int)xcd) nbx = c;
        }
        amask_s = am;
    }

    const f32x4 bias = *(const f32x4*)(bh + colf + l4 * 4);
    const int rowb = b0 + l15;            // this lane's batch row
    const int colb = colf + l4 * 4;       // this lane's first out-col

    // xi for t=0 (NT: streaming)
    f32x4 xiv = __builtin_nontemporal_load(
        (const f32x4*)(hs + (size_t)rowb * DLAT + colb));

    __syncthreads();
    const unsigned amask = amask_s;
    const int  myx  = lane & 7;
    const int  act  = (amask >> myx) & 1;
    const unsigned int* xsp = flags + F_XSTEP(myx);

    for (int t = 0; t < SEQ; ++t) {
        // prefetch xi for t+1
        f32x4 nx = (f32x4)0.f;
        if (t + 1 < SEQ)
            nx = __builtin_nontemporal_load(
                (const f32x4*)(hs + ((size_t)(t + 1) * BATCH + rowb) * DLAT + colb));

        const int cur = t & 1;
        f32x4 acc0 = (f32x4)0.f, acc1 = (f32x4)0.f;

        if (t > 0) {
            // ---- consumer spin: wave0, lanes watch xstep[lane&7] (sc1/MALL)
            if (w == 0) {
                const unsigned tgt = (unsigned)t;
                for (;;) {
                    unsigned f;
                    asm volatile("global_load_dword %0, %1, off sc1\n\t"
                                 "s_waitcnt vmcnt(0)"
                                 : "=v"(f) : "v"(xsp) : "memory");
                    if (__all(act ? (int)(f >= tgt) : 1)) break;
                }
            }
            __syncthreads();   // bar1: all XCDs flushed step t-1 to MALL

            // ---- stage h_prev 32 KB: hbuf[(t+1)&1] -> hT (sc1 loads, swizzle)
            const char* srcb = (const char*)hbuf
                             + ((size_t)((t + 1) & 1) * BATCH + b0) * DLAT * 2;
            const char* bp = srcb + tid * 16;
            u32x4 r[8];
            #pragma unroll
            for (int p = 0; p < 8; ++p)
                asm volatile("global_load_dwordx4 %0, %1, off sc1"
                             : "=v"(r[p]) : "v"(bp + p * 4096));
            asm volatile("s_waitcnt vmcnt(0)" ::: "memory");
            __builtin_amdgcn_sched_barrier(0);
            char* tb = (char*)hT;
            #pragma unroll
            for (int p = 0; p < 8; ++p) {
                const int c  = p * 256 + tid;
                const int rr = c >> 7;
                const int kb = (c & 127) * 16;
                *(bf16x8*)(tb + rr * 2048 + (kb ^ ((rr & 7) << 4))) = *(bf16x8*)&r[p];
            }
            __syncthreads();   // bar2: hT ready

            // ---- K-loop: A = W (LDS/regs), B = h (LDS, swizzled) ----
            const char* ta = (const char*)hT + l15 * 2048;
            const int sw = (l15 & 7) << 4;
            #pragma unroll
            for (int kk = 0; kk < KK_LDS; kk += 2) {
                bf16x8 h0 = *(const bf16x8*)(ta + ((kk * 64 + l4 * 16) ^ sw));
                bf16x8 h1 = *(const bf16x8*)(ta + (((kk + 1) * 64 + l4 * 16) ^ sw));
                bf16x8 w0 = *(const bf16x8*)&wl[w][kk][lane * 8];
                bf16x8 w1 = *(const bf16x8*)&wl[w][kk + 1][lane * 8];
                acc0 = __builtin_amdgcn_mfma_f32_16x16x32_bf16(w0, h0, acc0, 0, 0, 0);
                acc1 = __builtin_amdgcn_mfma_f32_16x16x32_bf16(w1, h1, acc1, 0, 0, 0);
            }
            #pragma unroll
            for (int r8i = 0; r8i < 8; r8i += 2) {
                const int kk = KK_LDS + r8i;
                bf16x8 h0 = *(const bf16x8*)(ta + ((kk * 64 + l4 * 16) ^ sw));
                bf16x8 h1 = *(const bf16x8*)(ta + (((kk + 1) * 64 + l4 * 16) ^ sw));
                acc0 = __builtin_amdgcn_mfma_f32_16x16x32_bf16(wreg[r8i],     h0, acc0, 0, 0, 0);
                acc1 = __builtin_amdgcn_mfma_f32_16x16x32_bf16(wreg[r8i + 1], h1, acc1, 0, 0, 0);
            }
        } else {
            __syncthreads();   // uniform shape at t=0
        }

        // ---- epilogue: tanh; NT f32x4 hs store; plain u64 hbuf store ----
        f32x4 ho;
        #pragma unroll
        for (int i = 0; i < 4; ++i) {
            float v = acc0[i] + acc1[i] + xiv[i] + bias[i];
            v = fminf(fmaxf(v, -15.f), 15.f);
            float e = __expf(2.f * v);
            ho[i] = 1.f - 2.f * __builtin_amdgcn_rcpf(e + 1.f);   // tanh(v)
        }
        __builtin_nontemporal_store(ho,
            (f32x4*)(hs + ((size_t)t * BATCH + rowb) * DLAT + colb));
        u64 pk =  (u64)f2bf(ho[0])        | ((u64)f2bf(ho[1]) << 16)
               | ((u64)f2bf(ho[2]) << 32) | ((u64)f2bf(ho[3]) << 48);
        *(u64*)(hbuf + ((size_t)cur * BATCH + rowb) * DLAT + colb) = pk;
        if (t == SEQ - 1)
            __builtin_nontemporal_store(ho,
                (f32x4*)(hfin + (size_t)rowb * DLAT + colb));

        // bar3: all 4 waves' stores vmcnt-drained -> in local L2
        __syncthreads();
        // ---- elected flusher: last same-XCD arriver flushes for everyone ----
        if (tid == 0 && t + 1 < SEQ) {
            unsigned old = __hip_atomic_fetch_add(flags + F_CNT(xcd), 1u,
                                                  __ATOMIC_RELAXED, __HIP_MEMORY_SCOPE_AGENT);
            if (old + 1 == nbx * (unsigned)(t + 1)) {
                __builtin_amdgcn_fence(__ATOMIC_RELEASE, "agent");  // wbl2: data->MALL
                *(volatile unsigned int*)(flags + F_XSTEP(xcd)) = (unsigned)(t + 1);
                __builtin_amdgcn_fence(__ATOMIC_RELEASE, "agent");  // wbl2: flag->MALL
            }
        }

        xiv = nx;
    }
}

extern "C" void kernel_launch(void* const* d_in, const int* in_sizes, int n_in,
                              void* d_out, int out_size, void* d_ws, size_t ws_size,
                              hipStream_t stream) {
    const float* x  = (const float*)d_in[0];
    const float* Wi = (const float*)d_in[1];
    const float* Wh = (const float*)d_in[2];
    const float* bh = (const float*)d_in[3];

    float* out  = (float*)d_out;
    float* hfin = out;                                  // [BATCH, DLAT]
    float* hs   = out + (size_t)BATCH * DLAT;           // [SEQ, BATCH, DLAT]

    unsigned int*   flags = (unsigned int*)d_ws;                          // 3.2 KB
    unsigned short* Wib   = (unsigned short*)((char*)d_ws + 4096);        // 1 MB
    unsigned short* Whb   = Wib + (size_t)DLAT * DIN;                     // 2 MB
    unsigned short* hbuf  = Whb + (size_t)DLAT * DLAT;                    // 1 MB

    convert_weights<<<512, 256, 0, stream>>>(Wi, Wh, Wib, Whb, flags);

    const int M = SEQ * BATCH;
    xproj_kernel<<<(M / 64) * (DLAT / 256), 1024, 0, stream>>>(x, Wib, hs);

    rnn_scan<<<NBLK, 256, 0, stream>>>(Whb, bh, hs, hfin, hbuf, flags);
}

// Round 12
// 1968.877 us; speedup vs baseline: 13.6210x; 1.5430x over previous
//
#include <hip/hip_runtime.h>
#include <hip/hip_bf16.h>

#define SEQ   512
#define BATCH 256
#define DIN   512
#define DLAT  1024

#define NBG    16                // batch groups of 16 rows
#define NCB    16                // blocks per bg, 64 cols each
#define NBLK   (NBG * NCB)       // 256
#define KK_LDS 24                // k-chunks of W in LDS (of 32); rest in regs

// flags u32 layout (each slot on its own 128B line):
//   [0]              g_total     (startup arrival, RMW only)
//   [32*(1+x)]       startcnt[x] (blocks on XCD x, RMW only)
//   [32*(9+x)]       cnt[x]      (per-step arrival, RMW only)
//   [32*(17+x)]      xstep[x]    (plain store + wbl2; sc1-load readers)
#define F_GTOT  0
#define F_SCNT(x) (32 * (1 + (x)))
#define F_CNT(x)  (32 * (9 + (x)))
#define F_XSTEP(x)(32 * (17 + (x)))
#define F_ZERO  800

typedef __attribute__((ext_vector_type(8))) short bf16x8;
typedef __attribute__((ext_vector_type(4))) float f32x4;
typedef __attribute__((ext_vector_type(4))) unsigned int u32x4;
typedef unsigned long long u64;

__device__ __forceinline__ unsigned short f2bf(float f) {
    union { float f; unsigned u; } v; v.f = f;
    unsigned r = v.u + 0x7FFFu + ((v.u >> 16) & 1u);   // RNE
    return (unsigned short)(r >> 16);
}

__global__ void convert_weights(const float* __restrict__ Wi, const float* __restrict__ Wh,
                                unsigned short* __restrict__ Wib, unsigned short* __restrict__ Whb,
                                unsigned int* __restrict__ flags) {
    const int nWi = DLAT * DIN;
    const int nWh = DLAT * DLAT;
    const int t0 = blockIdx.x * blockDim.x + threadIdx.x;
    if (t0 < F_ZERO) flags[t0] = 0;
    for (int idx = t0; idx < nWi + nWh; idx += gridDim.x * blockDim.x) {
        if (idx < nWi) Wib[idx] = f2bf(Wi[idx]);
        else           Whb[idx - nWi] = f2bf(Wh[idx - nWi]);
    }
}

// Phase 1: xi = x @ Wi^T, LDS-staged (fixes the 16-row-scattered loads of the
// old version: every global access is now >=128B-contiguous per segment).
// 4096 blocks = 1024 m-tiles(128) x 4 n-tiles(256), 512 thr = 8 waves (2m x 4n),
// each wave computes 64x64 via 4x4 16x16x32 MFMA frags, BK=64, XOR-swizzled
// LDS rows (conflict-free b128 frag reads). Superblock bid swizzle: 16
// consecutive bids = 4 m x 4 n sharing A-tiles (MALL) and B-slices (L2).
// Fragment lane-mapping and k-order identical to the r1-r10 xproj ->
// bit-identical xi. NT epilogue stores keep L2 clean.
__global__ __launch_bounds__(512) void xproj_kernel(const float* __restrict__ x,
                                                    const unsigned short* __restrict__ Wib,
                                                    float* __restrict__ xi) {
    __shared__ __align__(16) unsigned short aT[128][64];   // 16 KB, swizzled
    __shared__ __align__(16) unsigned short bT[256][64];   // 32 KB, swizzled

    const int tid  = threadIdx.x;
    const int lane = tid & 63;
    const int w    = tid >> 6;         // 0..7
    const int wm   = w & 1;            // 2 m-waves
    const int wn   = w >> 1;           // 4 n-waves
    const int l15  = lane & 15;
    const int l4   = lane >> 4;        // 0..3

    const int bid  = blockIdx.x;
    const int mblk = (bid >> 4) * 4 + (bid & 3);
    const int nblk = (bid >> 2) & 3;
    const size_t m0 = (size_t)mblk * 128;
    const int    n0 = nblk * 256;

    f32x4 acc[4][4];
    #pragma unroll
    for (int i = 0; i < 4; ++i)
        #pragma unroll
        for (int j = 0; j < 4; ++j) acc[i][j] = (f32x4)0.f;

    for (int k0 = 0; k0 < DIN; k0 += 64) {
        // ---- stage A: 128x64 f32 -> bf16 (RNE cvt inline, same as old path)
        #pragma unroll
        for (int p = 0; p < 4; ++p) {
            const int c  = p * 512 + tid;          // f32x4 chunk id 0..2047
            const int r  = c >> 4;                 // row 0..127
            const int co = (c & 15) * 4;           // f32 col 0..60
            f32x4 a = *(const f32x4*)(x + (m0 + r) * DIN + k0 + co);
            u64 pk =  (u64)f2bf(a[0])        | ((u64)f2bf(a[1]) << 16)
                   | ((u64)f2bf(a[2]) << 32) | ((u64)f2bf(a[3]) << 48);
            *(u64*)((char*)aT + r * 128 + ((co * 2) ^ ((r & 7) << 4))) = pk;
        }
        // ---- stage B: 256x64 bf16
        #pragma unroll
        for (int p = 0; p < 4; ++p) {
            const int c  = p * 512 + tid;          // 16B chunk id 0..2047
            const int r  = c >> 3;                 // row 0..255
            const int co = (c & 7) * 16;           // byte col 0..112
            bf16x8 b = *(const bf16x8*)(Wib + (size_t)(n0 + r) * DIN + k0 + (c & 7) * 8);
            *(bf16x8*)((char*)bT + r * 128 + (co ^ ((r & 7) << 4))) = b;
        }
        __syncthreads();

        #pragma unroll
        for (int kc = 0; kc < 2; ++kc) {
            bf16x8 af[4], bf[4];
            #pragma unroll
            for (int i = 0; i < 4; ++i) {
                const int r = wm * 64 + i * 16 + l15;
                af[i] = *(const bf16x8*)((char*)aT + r * 128
                                         + ((kc * 64 + l4 * 16) ^ ((r & 7) << 4)));
            }
            #pragma unroll
            for (int j = 0; j < 4; ++j) {
                const int r = wn * 64 + j * 16 + l15;
                bf[j] = *(const bf16x8*)((char*)bT + r * 128
                                         + ((kc * 64 + l4 * 16) ^ ((r & 7) << 4)));
            }
            #pragma unroll
            for (int i = 0; i < 4; ++i)
                #pragma unroll
                for (int j = 0; j < 4; ++j)
                    acc[i][j] = __builtin_amdgcn_mfma_f32_16x16x32_bf16(af[i], bf[j], acc[i][j], 0, 0, 0);
        }
        __syncthreads();
    }

    // ---- epilogue: NT stores (same index mapping as the validated old xproj)
    #pragma unroll
    for (int j = 0; j < 4; ++j) {
        const int col = n0 + wn * 64 + j * 16 + l15;
        #pragma unroll
        for (int i = 0; i < 4; ++i) {
            const size_t mr = m0 + wm * 64 + i * 16 + l4 * 4;
            #pragma unroll
            for (int ii = 0; ii < 4; ++ii)
                __builtin_nontemporal_store(acc[i][j][ii], xi + (mr + ii) * DLAT + col);
        }
    }
}

// Phase 2: 256 blocks, 256 thr (4 waves), 1 block/CU (128 KiB LDS).
// VERBATIM round-10 (proven): elected per-XCD flusher, 2 wbl2/XCD/step.
// gfx950 model (r5-r10): stores/RMWs land dirty in local XCD L2; wbl2 pushes
// to MALL; sc1 loads read MALL; RMW-written data must be read by RMWs.
__global__ __launch_bounds__(256, 1) void rnn_scan(
        const unsigned short* __restrict__ Whb,
        const float* __restrict__ bh,
        float* __restrict__ hs,                 // xi on entry; overwritten with h
        float* __restrict__ hfin,
        unsigned short* __restrict__ hbuf,      // [2][BATCH][DLAT] bf16
        unsigned int* __restrict__ flags) {
    __shared__ __align__(16) unsigned short hT[16][1024];          // 32 KB
    __shared__ __align__(16) unsigned short wl[4][KK_LDS][512];    // 96 KB
    __shared__ unsigned amask_s;

    const int tid  = threadIdx.x;
    const int lane = tid & 63;
    const int w    = tid >> 6;        // 0..3
    const int l15  = lane & 15;
    const int l4   = lane >> 4;       // 0..3
    const int bid  = blockIdx.x;
    const int bg   = bid & 15;        // 0..15
    const int cbk  = bid >> 4;        // 0..15
    const int b0   = bg * 16;
    const int colf = cbk * 64 + w * 16;     // wave's 16-col tile base

    // ---- W fill: LDS part (each wave its own region) ----
    #pragma unroll
    for (int kk = 0; kk < KK_LDS; ++kk)
        *(bf16x8*)&wl[w][kk][lane * 8] =
            *(const bf16x8*)(Whb + (size_t)(colf + l15) * DLAT + kk * 32 + l4 * 8);
    // ---- W tail: 8 k-chunks in registers ----
    bf16x8 wreg[8];
    #pragma unroll
    for (int r = 0; r < 8; ++r)
        wreg[r] = *(const bf16x8*)(Whb + (size_t)(colf + l15) * DLAT
                                   + (KK_LDS + r) * 32 + l4 * 8);

    // ---- startup census (RMW-only) ----
    unsigned xcd = 0, nbx = 0;
    if (tid == 0) {
        asm volatile("s_getreg_b32 %0, hwreg(HW_REG_XCC_ID)" : "=s"(xcd));
        xcd &= 7;
        __hip_atomic_fetch_add(flags + F_SCNT(xcd), 1u, __ATOMIC_RELAXED,
                               __HIP_MEMORY_SCOPE_AGENT);
        __hip_atomic_fetch_add(flags + F_GTOT, 1u, __ATOMIC_RELAXED,
                               __HIP_MEMORY_SCOPE_AGENT);
        while (__hip_atomic_fetch_add(flags + F_GTOT, 0u, __ATOMIC_RELAXED,
                                      __HIP_MEMORY_SCOPE_AGENT) < NBLK)
            __builtin_amdgcn_s_sleep(32);
        unsigned am = 0;
        #pragma unroll
        for (int x2 = 0; x2 < 8; ++x2) {
            unsigned c = __hip_atomic_fetch_add(flags + F_SCNT(x2), 0u,
                                                __ATOMIC_RELAXED, __HIP_MEMORY_SCOPE_AGENT);
            if (c) am |= 1u << x2;
            if (x2 == (int)xcd) nbx = c;
        }
        amask_s = am;
    }

    const f32x4 bias = *(const f32x4*)(bh + colf + l4 * 4);
    const int rowb = b0 + l15;            // this lane's batch row
    const int colb = colf + l4 * 4;       // this lane's first out-col

    // xi for t=0 (NT: streaming)
    f32x4 xiv = __builtin_nontemporal_load(
        (const f32x4*)(hs + (size_t)rowb * DLAT + colb));

    __syncthreads();
    const unsigned amask = amask_s;
    const int  myx  = lane & 7;
    const int  act  = (amask >> myx) & 1;
    const unsigned int* xsp = flags + F_XSTEP(myx);

    for (int t = 0; t < SEQ; ++t) {
        // prefetch xi for t+1
        f32x4 nx = (f32x4)0.f;
        if (t + 1 < SEQ)
            nx = __builtin_nontemporal_load(
                (const f32x4*)(hs + ((size_t)(t + 1) * BATCH + rowb) * DLAT + colb));

        const int cur = t & 1;
        f32x4 acc0 = (f32x4)0.f, acc1 = (f32x4)0.f;

        if (t > 0) {
            // ---- consumer spin: wave0, lanes watch xstep[lane&7] (sc1/MALL)
            if (w == 0) {
                const unsigned tgt = (unsigned)t;
                for (;;) {
                    unsigned f;
                    asm volatile("global_load_dword %0, %1, off sc1\n\t"
                                 "s_waitcnt vmcnt(0)"
                                 : "=v"(f) : "v"(xsp) : "memory");
                    if (__all(act ? (int)(f >= tgt) : 1)) break;
                }
            }
            __syncthreads();   // bar1: all XCDs flushed step t-1 to MALL

            // ---- stage h_prev 32 KB: hbuf[(t+1)&1] -> hT (sc1 loads, swizzle)
            const char* srcb = (const char*)hbuf
                             + ((size_t)((t + 1) & 1) * BATCH + b0) * DLAT * 2;
            const char* bp = srcb + tid * 16;
            u32x4 r[8];
            #pragma unroll
            for (int p = 0; p < 8; ++p)
                asm volatile("global_load_dwordx4 %0, %1, off sc1"
                             : "=v"(r[p]) : "v"(bp + p * 4096));
            asm volatile("s_waitcnt vmcnt(0)" ::: "memory");
            __builtin_amdgcn_sched_barrier(0);
            char* tb = (char*)hT;
            #pragma unroll
            for (int p = 0; p < 8; ++p) {
                const int c  = p * 256 + tid;
                const int rr = c >> 7;
                const int kb = (c & 127) * 16;
                *(bf16x8*)(tb + rr * 2048 + (kb ^ ((rr & 7) << 4))) = *(bf16x8*)&r[p];
            }
            __syncthreads();   // bar2: hT ready

            // ---- K-loop: A = W (LDS/regs), B = h (LDS, swizzled) ----
            const char* ta = (const char*)hT + l15 * 2048;
            const int sw = (l15 & 7) << 4;
            #pragma unroll
            for (int kk = 0; kk < KK_LDS; kk += 2) {
                bf16x8 h0 = *(const bf16x8*)(ta + ((kk * 64 + l4 * 16) ^ sw));
                bf16x8 h1 = *(const bf16x8*)(ta + (((kk + 1) * 64 + l4 * 16) ^ sw));
                bf16x8 w0 = *(const bf16x8*)&wl[w][kk][lane * 8];
                bf16x8 w1 = *(const bf16x8*)&wl[w][kk + 1][lane * 8];
                acc0 = __builtin_amdgcn_mfma_f32_16x16x32_bf16(w0, h0, acc0, 0, 0, 0);
                acc1 = __builtin_amdgcn_mfma_f32_16x16x32_bf16(w1, h1, acc1, 0, 0, 0);
            }
            #pragma unroll
            for (int r8i = 0; r8i < 8; r8i += 2) {
                const int kk = KK_LDS + r8i;
                bf16x8 h0 = *(const bf16x8*)(ta + ((kk * 64 + l4 * 16) ^ sw));
                bf16x8 h1 = *(const bf16x8*)(ta + (((kk + 1) * 64 + l4 * 16) ^ sw));
                acc0 = __builtin_amdgcn_mfma_f32_16x16x32_bf16(wreg[r8i],     h0, acc0, 0, 0, 0);
                acc1 = __builtin_amdgcn_mfma_f32_16x16x32_bf16(wreg[r8i + 1], h1, acc1, 0, 0, 0);
            }
        } else {
            __syncthreads();   // uniform shape at t=0
        }

        // ---- epilogue: tanh; NT f32x4 hs store; plain u64 hbuf store ----
        f32x4 ho;
        #pragma unroll
        for (int i = 0; i < 4; ++i) {
            float v = acc0[i] + acc1[i] + xiv[i] + bias[i];
            v = fminf(fmaxf(v, -15.f), 15.f);
            float e = __expf(2.f * v);
            ho[i] = 1.f - 2.f * __builtin_amdgcn_rcpf(e + 1.f);   // tanh(v)
        }
        __builtin_nontemporal_store(ho,
            (f32x4*)(hs + ((size_t)t * BATCH + rowb) * DLAT + colb));
        u64 pk =  (u64)f2bf(ho[0])        | ((u64)f2bf(ho[1]) << 16)
               | ((u64)f2bf(ho[2]) << 32) | ((u64)f2bf(ho[3]) << 48);
        *(u64*)(hbuf + ((size_t)cur * BATCH + rowb) * DLAT + colb) = pk;
        if (t == SEQ - 1)
            __builtin_nontemporal_store(ho,
                (f32x4*)(hfin + (size_t)rowb * DLAT + colb));

        // bar3: all 4 waves' stores vmcnt-drained -> in local L2
        __syncthreads();
        // ---- elected flusher: last same-XCD arriver flushes for everyone ----
        if (tid == 0 && t + 1 < SEQ) {
            unsigned old = __hip_atomic_fetch_add(flags + F_CNT(xcd), 1u,
                                                  __ATOMIC_RELAXED, __HIP_MEMORY_SCOPE_AGENT);
            if (old + 1 == nbx * (unsigned)(t + 1)) {
                __builtin_amdgcn_fence(__ATOMIC_RELEASE, "agent");  // wbl2: data->MALL
                *(volatile unsigned int*)(flags + F_XSTEP(xcd)) = (unsigned)(t + 1);
                __builtin_amdgcn_fence(__ATOMIC_RELEASE, "agent");  // wbl2: flag->MALL
            }
        }

        xiv = nx;
    }
}

extern "C" void kernel_launch(void* const* d_in, const int* in_sizes, int n_in,
                              void* d_out, int out_size, void* d_ws, size_t ws_size,
                              hipStream_t stream) {
    const float* x  = (const float*)d_in[0];
    const float* Wi = (const float*)d_in[1];
    const float* Wh = (const float*)d_in[2];
    const float* bh = (const float*)d_in[3];

    float* out  = (float*)d_out;
    float* hfin = out;                                  // [BATCH, DLAT]
    float* hs   = out + (size_t)BATCH * DLAT;           // [SEQ, BATCH, DLAT]

    unsigned int*   flags = (unsigned int*)d_ws;                          // 3.2 KB
    unsigned short* Wib   = (unsigned short*)((char*)d_ws + 4096);        // 1 MB
    unsigned short* Whb   = Wib + (size_t)DLAT * DIN;                     // 2 MB
    unsigned short* hbuf  = Whb + (size_t)DLAT * DLAT;                    // 1 MB

    convert_weights<<<512, 256, 0, stream>>>(Wi, Wh, Wib, Whb, flags);

    const int M = SEQ * BATCH;
    xproj_kernel<<<(M / 128) * (DLAT / 256), 512, 0, stream>>>(x, Wib, hs);

    rnn_scan<<<NBLK, 256, 0, stream>>>(Whb, bh, hs, hfin, hbuf, flags);
}